// Round 24
// baseline (114.575 us; speedup 1.0000x reference)
//
#include <hip/hip_runtime.h>
#include <math.h>

// Problem constants: B=2, T=2048, C=1024, H=16, D=64
constexpr int Bb = 2;
constexpr int Tt = 2048;
constexpr int Cc = 1024;
constexpr int Hh = 16;
constexpr int M_ROWS = Bb * Tt;          // 4096
constexpr float EPSV = 1e-5f;

typedef __attribute__((ext_vector_type(4))) float f32x4;
typedef __attribute__((ext_vector_type(8))) __bf16 bf16x8;
using u16 = unsigned short;

union Frag8 {
    u16 u[8];
    unsigned int ui[4];
    uint4 v;
    bf16x8 b;
};

// fp32 -> bf16 round-to-nearest-even
__device__ __forceinline__ u16 f2bf(float f) {
    union { float f; unsigned int u; } c;
    c.f = f;
    unsigned int r = (c.u + 0x7fffu + ((c.u >> 16) & 1u)) >> 16;
    return (u16)r;
}
__device__ __forceinline__ float bf2f(u16 u) {
    union { unsigned int i; float f; } c;
    c.i = ((unsigned int)u) << 16;
    return c.f;
}

// async global->LDS, 16 B per lane; LDS dest = wave-uniform base + lane*16
__device__ __forceinline__ void gload_lds16(const void* g, void* l) {
    __builtin_amdgcn_global_load_lds(
        (__attribute__((address_space(1))) void*)const_cast<void*>(g),
        (__attribute__((address_space(3))) void*)l, 16, 0, 0);
}

// ---------------------------------------------------------------------------
// Prep (merged): weight bf16 converts + RoPE tables [T][32] + RMSNorm.
// Grid 8448 x 256: [0,3072) w_qkv, [3072,4096) w_o, [4096,4352) tables,
// [4352,8448) rmsnorm (one block per row).
// ---------------------------------------------------------------------------
__global__ __launch_bounds__(256) void prep_k(const float* __restrict__ w_qkv,
                                              u16* __restrict__ wqkv_bf,
                                              const float* __restrict__ w_o,
                                              u16* __restrict__ wo_bf,
                                              float* __restrict__ cosT,
                                              float* __restrict__ sinT,
                                              const float* __restrict__ x,
                                              const float* __restrict__ rms_w,
                                              u16* __restrict__ xn) {
    __shared__ float ws_[4];
    int blk = blockIdx.x;
    int tid = threadIdx.x;
    if (blk < 3072) {
        int i = (blk * 256 + tid) * 4;
        float4 v = *(const float4*)&w_qkv[i];
        ushort4 o;
        o.x = f2bf(v.x); o.y = f2bf(v.y); o.z = f2bf(v.z); o.w = f2bf(v.w);
        *(ushort4*)&wqkv_bf[i] = o;
    } else if (blk < 4096) {
        int i = ((blk - 3072) * 256 + tid) * 4;
        float4 v = *(const float4*)&w_o[i];
        ushort4 o;
        o.x = f2bf(v.x); o.y = f2bf(v.y); o.z = f2bf(v.z); o.w = f2bf(v.w);
        *(ushort4*)&wo_bf[i] = o;
    } else if (blk < 4352) {
        int lin = (blk - 4096) * 256 + tid;   // 0..65535 = t*32+j
        int tt = lin >> 5, j = lin & 31;
        float inv = exp2f(-(float)j * (log2f(10000.0f) / 32.0f));
        float a = (float)tt * inv;
        cosT[lin] = cosf(a);
        sinT[lin] = sinf(a);
    } else {
        int row = blk - 4352;
        const float* xr = x + (size_t)row * Cc;
        float4 v = *(const float4*)&xr[tid * 4];
        float ss = v.x * v.x + v.y * v.y + v.z * v.z + v.w * v.w;
        #pragma unroll
        for (int off = 32; off > 0; off >>= 1) ss += __shfl_down(ss, off);
        if ((tid & 63) == 0) ws_[tid >> 6] = ss;
        __syncthreads();
        float tot = ws_[0] + ws_[1] + ws_[2] + ws_[3];
        float r = rsqrtf(tot * (1.0f / (float)Cc) + EPSV);
        float4 wv = *(const float4*)&rms_w[tid * 4];
        ushort4 o;
        o.x = f2bf(v.x * r * wv.x);
        o.y = f2bf(v.y * r * wv.y);
        o.z = f2bf(v.z * r * wv.z);
        o.w = f2bf(v.w * r * wv.w);
        *(ushort4*)&xn[(size_t)row * Cc + tid * 4] = o;
    }
}

// ---------------------------------------------------------------------------
// bf16 MFMA GEMM v2 (R19 winner): 128x64 tile, BK=64, 4 waves, 24KB LDS ->
// 6 blocks/CU. 2-barrier skeleton + source-chunk XOR swizzle (rule #21).
// ---------------------------------------------------------------------------
template<bool BF16OUT>
__global__ __launch_bounds__(256) void gemm_mfma_k(const u16* __restrict__ A,
                                                   const u16* __restrict__ W,
                                                   const float* __restrict__ bias,
                                                   void* __restrict__ Ov,
                                                   int M, int N, int K) {
    __shared__ __align__(16) u16 As[128 * 64];   // 16 KB
    __shared__ __align__(16) u16 Bs[64 * 64];    // 8 KB

    const int tid = threadIdx.x;
    const int w = tid >> 6;
    const int l = tid & 63;
    const int wr = w >> 1;
    const int wc = w & 1;
    const int q = l & 15;
    const int g = l >> 4;

    const int m0 = blockIdx.y * 128;
    const int n0 = blockIdx.x * 64;

    const int srow = l >> 3;
    const int cph = l & 7;
    const int cl = cph ^ srow;

    f32x4 acc[4][2];
    #pragma unroll
    for (int i = 0; i < 4; ++i)
        #pragma unroll
        for (int j = 0; j < 2; ++j)
            acc[i][j] = (f32x4){0.f, 0.f, 0.f, 0.f};

    const int nkt = K >> 6;
    for (int kt = 0; kt < nkt; ++kt) {
        const int k0 = kt << 6;
        __syncthreads();
        #pragma unroll
        for (int iss = 0; iss < 4; ++iss) {
            int r = w * 32 + iss * 8 + srow;
            gload_lds16(A + (size_t)(m0 + r) * K + k0 + cl * 8,
                        &As[(w * 32 + iss * 8) * 64]);
        }
        #pragma unroll
        for (int iss = 0; iss < 2; ++iss) {
            int r = w * 16 + iss * 8 + srow;
            gload_lds16(W + (size_t)(n0 + r) * K + k0 + cl * 8,
                        &Bs[(w * 16 + iss * 8) * 64]);
        }
        __syncthreads();

        #pragma unroll
        for (int kk = 0; kk < 2; ++kk) {
            Frag8 af[4], bf[2];
            const int ca = kk * 4 + g;
            #pragma unroll
            for (int i = 0; i < 4; ++i) {
                int ra = wr * 64 + i * 16 + q;
                af[i] = *(const Frag8*)&As[ra * 64 + ((ca ^ (ra & 7)) * 8)];
            }
            #pragma unroll
            for (int j = 0; j < 2; ++j) {
                int rb = wc * 32 + j * 16 + q;
                bf[j] = *(const Frag8*)&Bs[rb * 64 + ((ca ^ (rb & 7)) * 8)];
            }
            #pragma unroll
            for (int i = 0; i < 4; ++i)
                #pragma unroll
                for (int j = 0; j < 2; ++j)
                    acc[i][j] = __builtin_amdgcn_mfma_f32_16x16x32_bf16(
                        af[i].b, bf[j].b, acc[i][j], 0, 0, 0);
        }
    }

    #pragma unroll
    for (int i = 0; i < 4; ++i) {
        int row = m0 + wr * 64 + i * 16 + g * 4;
        #pragma unroll
        for (int j = 0; j < 2; ++j) {
            int col = n0 + wc * 32 + j * 16 + q;
            float bb = bias[col];
            #pragma unroll
            for (int r2 = 0; r2 < 4; ++r2) {
                float val = acc[i][j][r2] + bb;
                if (BF16OUT)
                    ((u16*)Ov)[(size_t)(row + r2) * N + col] = f2bf(val);
                else
                    ((float*)Ov)[(size_t)(row + r2) * N + col] = val;
            }
        }
    }
}

// ---------------------------------------------------------------------------
// RoPE + repack v2: qkv_bf16 [b,t,3,h,64] ->
//   Qb [bh][t][64] bf16 (Q pre-scaled by 0.125*log2e)  [unchanged layout]
//   KL [bh][tile][kk*4+g][lane][8] bf16  -- FRAGMENT-MAJOR: attention's QK
//     A-fragment (kk,g) for lane (g2,q15) is one coalesced 16B/lane load.
//     element(kk,g,lane=(g2,q15),e) = K_roped[g*16+q15][kk*32+g2*8+e]
//   VL [bh][tile][kk*4+dg][lane][8] bf16 -- same for PV B-fragment, with the
//     pi key permutation folded in:
//     element(kk,dg,lane,e) = V^T[dg*16+q15][pi-slot kk*32+g2*8+e]
// Per-tile stride for KL/VL: 8 frags * 512 u16 = 4096 u16 (8 KB).
// ---------------------------------------------------------------------------
__global__ __launch_bounds__(256) void rope_pack_k(const u16* __restrict__ qkv,
                                                   const float* __restrict__ cosT,
                                                   const float* __restrict__ sinT,
                                                   u16* __restrict__ Qb,
                                                   u16* __restrict__ KL,
                                                   u16* __restrict__ VL) {
    const int jt = blockIdx.x;          // tile 0..31
    const int t0 = jt * 64;
    const int h = blockIdx.y, b = blockIdx.z;
    const int t = threadIdx.x;
    const int bh = b * Hh + h;
    __shared__ u16 Vs[64 * 64];
    constexpr float QSC = 0.125f * 1.44269504089f;   // 1/sqrt(D) * log2(e)
    const size_t tilebase = ((size_t)bh * 32 + jt) * 4096;

    // ---- stage V tile to LDS (row-major, bf16 passthrough) ----
    {
        int row = t >> 2, d16 = (t & 3) * 16;
        const u16* vp = qkv + (size_t)(b * Tt + t0 + row) * 3072 + 2048 + h * 64 + d16;
        *(uint4*)&Vs[row * 64 + d16]     = *(const uint4*)vp;
        *(uint4*)&Vs[row * 64 + d16 + 8] = *(const uint4*)(vp + 8);
    }

    // ---- RoPE on Q and K ----
    {
        int row = t >> 2, d0 = (t & 3) * 8;
        int g = row >> 4, q15 = row & 15, g2 = t & 3;
        size_t rb = (size_t)(b * Tt + t0 + row) * 3072 + h * 64;
        const u16* qp = qkv + rb;
        const u16* kp = qkv + rb + 1024;
        Frag8 qlo, qhi, klo, khi;
        qlo.v = *(const uint4*)&qp[d0];
        qhi.v = *(const uint4*)&qp[d0 + 32];
        klo.v = *(const uint4*)&kp[d0];
        khi.v = *(const uint4*)&kp[d0 + 32];
        const float* cp = &cosT[(t0 + row) * 32 + d0];
        const float* sp = &sinT[(t0 + row) * 32 + d0];
        float4 c0 = *(const float4*)cp, c1 = *(const float4*)(cp + 4);
        float4 s0 = *(const float4*)sp, s1 = *(const float4*)(sp + 4);
        float cc[8] = {c0.x, c0.y, c0.z, c0.w, c1.x, c1.y, c1.z, c1.w};
        float ss[8] = {s0.x, s0.y, s0.z, s0.w, s1.x, s1.y, s1.z, s1.w};
        Frag8 oql, oqh, okl, okh;
        #pragma unroll
        for (int i = 0; i < 8; ++i) {
            float ql = bf2f(qlo.u[i]), qh = bf2f(qhi.u[i]);
            float kl = bf2f(klo.u[i]), kh = bf2f(khi.u[i]);
            oql.u[i] = f2bf((ql * cc[i] - qh * ss[i]) * QSC);
            oqh.u[i] = f2bf((qh * cc[i] + ql * ss[i]) * QSC);
            okl.u[i] = f2bf(kl * cc[i] - kh * ss[i]);
            okh.u[i] = f2bf(kh * cc[i] + kl * ss[i]);
        }
        // Q: head-major rows (unchanged layout)
        u16* qd = Qb + ((size_t)bh * Tt + t0 + row) * 64;
        *(uint4*)&qd[d0]      = oql.v;
        *(uint4*)&qd[d0 + 32] = oqh.v;
        // K: fragment-major. okl covers d in [g2*8, g2*8+8) -> (kk=0, chunk g2);
        //    okh covers d+32 -> (kk=1, chunk g2).
        *(uint4*)&KL[tilebase + (size_t)(0 * 4 + g) * 512 + (g2 * 16 + q15) * 8] = okl.v;
        *(uint4*)&KL[tilebase + (size_t)(1 * 4 + g) * 512 + (g2 * 16 + q15) * 8] = okh.v;
    }
    __syncthreads();

    // ---- V out: fragment-major with pi-permuted key slots ----
    {
        int d = t >> 2, kq = (t & 3) * 16;
        int dg = d >> 4, q15v = d & 15;
        int kkv = (t & 3) >> 1;            // slots >= 32 -> kk=1
        int g2a = ((t & 3) & 1) * 2;       // first chunk within this 16-slot run
        Frag8 a, b2;
        #pragma unroll
        for (int j = 0; j < 16; ++j) {
            int slot = kq + j;
            int key = ((slot >> 5) * 2 + ((slot >> 2) & 1)) * 16
                    + ((slot >> 3) & 3) * 4 + (slot & 3);
            u16 vv = Vs[key * 64 + d];
            if (j < 8) a.u[j] = vv; else b2.u[j - 8] = vv;
        }
        u16* base = VL + tilebase + (size_t)(kkv * 4 + dg) * 512;
        *(uint4*)&base[(g2a * 16 + q15v) * 8]       = a.v;
        *(uint4*)&base[((g2a + 1) * 16 + q15v) * 8] = b2.v;
    }
}

// ---------------------------------------------------------------------------
// MFMA flash attention v13: ZERO-LDS, ZERO-BARRIER. K/V fragments stream
// directly from L2 in fragment-major order (KL/VL): each MFMA operand is one
// fully-coalesced 16B/lane global load. Waves are fully independent -- no
// __syncthreads, no LDS; latency hidden by TLP + compiler load/MFMA
// interleave. Per-bh K/V = 512 KB (L2-resident; ~33x reuse through L2).
// Block = 4 waves, one q-tile c (wave w4 owns rows w4*16..+15); grid 1024
// heavy-first balanced. Softmax machinery = v9 (static-shift, pi-Vt
// zero-shuffle PV, ones-MFMA l-sum, setprio).
// ---------------------------------------------------------------------------
__global__ __launch_bounds__(256) void attn_mfma_k(const u16* __restrict__ Qb,
                                                   const u16* __restrict__ KL,
                                                   const u16* __restrict__ VL,
                                                   u16* __restrict__ out) {
    const int i = blockIdx.x;           // 0..1023
    int c, bh;
    if (i < 512) { c = 31 - (i >> 5); bh = i & 31; }        // heavy first
    else         { int k = i - 512; c = k >> 5; bh = k & 31; }
    const int b = bh >> 4, h = bh & 15;

    const int t = threadIdx.x;
    const int w4 = t >> 6;       // wave 0..3
    const int l = t & 63;
    const int q15 = l & 15;
    const int g2 = l >> 4;

    // ---- Q fragments (exp2-domain scale pre-folded) ----
    Frag8 qf[2];
    {
        int qrow = c * 64 + w4 * 16 + q15;
        const u16* qp = Qb + ((size_t)bh * Tt + qrow) * 64;
        qf[0] = *(const Frag8*)&qp[g2 * 8];
        qf[1] = *(const Frag8*)&qp[32 + g2 * 8];
    }

    Frag8 ones;
    #pragma unroll
    for (int e = 0; e < 8; ++e) ones.u[e] = 0x3F80;   // bf16 1.0

    f32x4 acco[4];
    #pragma unroll
    for (int dg = 0; dg < 4; ++dg) acco[dg] = (f32x4){0.f, 0.f, 0.f, 0.f};
    f32x4 acc_l = (f32x4){0.f, 0.f, 0.f, 0.f};

    // fragment-major bases; lane offset l*8 u16 = 16B, contiguous per wave.
    // Split into lo/hi (+4KB) so the 13-bit signed inst offsets stay in range.
    const u16* kp0 = KL + ((size_t)bh * 32) * 4096 + l * 8;
    const u16* kp1 = kp0 + 2048;     // frags 4..7 (u16 units: 4*512)
    const u16* vp0 = VL + ((size_t)bh * 32) * 4096 + l * 8;
    const u16* vp1 = vp0 + 2048;

    for (int j = 0; j <= c; ++j) {
        // ---- QK^T (swapped): S^T[key][q], log2 domain ----
        Frag8 kf[2][4];
        #pragma unroll
        for (int g = 0; g < 4; ++g) {
            kf[0][g] = *(const Frag8*)&kp0[g * 512];
            kf[1][g] = *(const Frag8*)&kp1[g * 512];
        }
        f32x4 sacc[4];
        __builtin_amdgcn_s_setprio(1);
        #pragma unroll
        for (int g = 0; g < 4; ++g) {
            sacc[g] = (f32x4){0.f, 0.f, 0.f, 0.f};
            sacc[g] = __builtin_amdgcn_mfma_f32_16x16x32_bf16(
                kf[0][g].b, qf[0].b, sacc[g], 0, 0, 0);
            sacc[g] = __builtin_amdgcn_mfma_f32_16x16x32_bf16(
                kf[1][g].b, qf[1].b, sacc[g], 0, 0, 0);
        }
        __builtin_amdgcn_s_setprio(0);
        if (j == c) {   // diagonal tile: causal mask (true key order)
            #pragma unroll
            for (int g = 0; g < 4; ++g)
                #pragma unroll
                for (int r = 0; r < 4; ++r)
                    if (g * 16 + g2 * 4 + r > w4 * 16 + q15) sacc[g][r] = -1e30f;
        }

        // ---- P = exp2(S) straight into PV A-fragments (pi-VL) ----
        Frag8 pa[2];
        #pragma unroll
        for (int kk = 0; kk < 2; ++kk)
            #pragma unroll
            for (int e = 0; e < 8; ++e)
                pa[kk].b[e] = (__bf16)exp2f(sacc[2 * kk + (e >> 2)][e & 3]);

        // ---- l-sum + PV ----
        Frag8 vf[2][4];
        #pragma unroll
        for (int dg = 0; dg < 4; ++dg) {
            vf[0][dg] = *(const Frag8*)&vp0[dg * 512];
            vf[1][dg] = *(const Frag8*)&vp1[dg * 512];
        }
        __builtin_amdgcn_s_setprio(1);
        acc_l = __builtin_amdgcn_mfma_f32_16x16x32_bf16(pa[0].b, ones.b, acc_l, 0, 0, 0);
        acc_l = __builtin_amdgcn_mfma_f32_16x16x32_bf16(pa[1].b, ones.b, acc_l, 0, 0, 0);
        #pragma unroll
        for (int dg = 0; dg < 4; ++dg) {
            acco[dg] = __builtin_amdgcn_mfma_f32_16x16x32_bf16(
                pa[0].b, vf[0][dg].b, acco[dg], 0, 0, 0);
            acco[dg] = __builtin_amdgcn_mfma_f32_16x16x32_bf16(
                pa[1].b, vf[1][dg].b, acco[dg], 0, 0, 0);
        }
        __builtin_amdgcn_s_setprio(0);

        kp0 += 4096; kp1 += 4096;
        vp0 += 4096; vp1 += 4096;
    }

    // ---- epilogue: acc_l[r] is the row sum for row g2*4+r ----
    float lr[4];
    #pragma unroll
    for (int r = 0; r < 4; ++r) lr[r] = 1.f / acc_l[r];
    const int qbase = c * 64 + w4 * 16;
    #pragma unroll
    for (int dg = 0; dg < 4; ++dg)
        #pragma unroll
        for (int r = 0; r < 4; ++r)
            out[((size_t)(b * Tt + qbase + g2 * 4 + r)) * Cc + h * 64 + dg * 16 + q15] =
                f2bf(acco[dg][r] * lr[r]);
}

// ---------------------------------------------------------------------------
// Launch
// ---------------------------------------------------------------------------
extern "C" void kernel_launch(void* const* d_in, const int* in_sizes, int n_in,
                              void* d_out, int out_size, void* d_ws, size_t ws_size,
                              hipStream_t stream) {
    const float* x      = (const float*)d_in[0];
    const float* w_qkv  = (const float*)d_in[2];
    const float* b_qkv  = (const float*)d_in[3];
    const float* w_o    = (const float*)d_in[4];
    const float* b_o    = (const float*)d_in[5];
    const float* rms_w  = (const float*)d_in[6];
    float* out = (float*)d_out;

    char* ws = (char*)d_ws;
    u16*   xn_bf   = (u16*)ws;                                   // 8 MB [0,8)
    u16*   KL      = (u16*)(ws + (size_t)(8 << 20));             // 8 MB [8,16)
    u16*   VL      = (u16*)(ws + (size_t)(16 << 20));            // 8 MB [16,24)
    u16*   Qb      = (u16*)(ws + (size_t)(24 << 20));            // 8 MB [24,32)
    u16*   qkvb    = (u16*)(ws + (size_t)(32 << 20));            // 24 MB [32,56)
    u16*   wqkv_bf = (u16*)(ws + (size_t)(56 << 20));            // 6 MB [56,62)
    u16*   wo_bf   = (u16*)(ws + (size_t)(62 << 20));            // 2 MB [62,64)
    float* cosT    = (float*)(ws + (size_t)(64 << 20));          // 256 KB
    float* sinT    = (float*)(ws + (size_t)(64 << 20) + (1 << 18));
    u16*   attn_bf = xn_bf;   // xn dead after QKV GEMM

    prep_k<<<dim3(8448), dim3(256), 0, stream>>>(w_qkv, wqkv_bf, w_o, wo_bf,
                                                 cosT, sinT, x, rms_w, xn_bf);
    gemm_mfma_k<true><<<dim3(3 * Cc / 64, M_ROWS / 128), dim3(256), 0, stream>>>(
        xn_bf, wqkv_bf, b_qkv, qkvb, M_ROWS, 3 * Cc, Cc);
    rope_pack_k<<<dim3(Tt / 64, Hh, Bb), dim3(256), 0, stream>>>(
        qkvb, cosT, sinT, Qb, KL, VL);
    attn_mfma_k<<<dim3(1024), dim3(256), 0, stream>>>(Qb, KL, VL, attn_bf);
    gemm_mfma_k<false><<<dim3(Cc / 64, M_ROWS / 128), dim3(256), 0, stream>>>(
        attn_bf, wo_bf, b_o, out, M_ROWS, Cc, Cc);
}

// Round 25
// 114.151 us; speedup vs baseline: 1.0037x; 1.0037x over previous
//
#include <hip/hip_runtime.h>
#include <math.h>

// Problem constants: B=2, T=2048, C=1024, H=16, D=64
constexpr int Bb = 2;
constexpr int Tt = 2048;
constexpr int Cc = 1024;
constexpr int Hh = 16;
constexpr int M_ROWS = Bb * Tt;          // 4096
constexpr float EPSV = 1e-5f;

typedef __attribute__((ext_vector_type(4))) float f32x4;
typedef __attribute__((ext_vector_type(8))) __bf16 bf16x8;
using u16 = unsigned short;

union Frag8 {
    u16 u[8];
    unsigned int ui[4];
    uint4 v;
    bf16x8 b;
};

// fp32 -> bf16 round-to-nearest-even
__device__ __forceinline__ u16 f2bf(float f) {
    union { float f; unsigned int u; } c;
    c.f = f;
    unsigned int r = (c.u + 0x7fffu + ((c.u >> 16) & 1u)) >> 16;
    return (u16)r;
}
__device__ __forceinline__ float bf2f(u16 u) {
    union { unsigned int i; float f; } c;
    c.i = ((unsigned int)u) << 16;
    return c.f;
}

// async global->LDS, 16 B per lane; LDS dest = wave-uniform base + lane*16
__device__ __forceinline__ void gload_lds16(const void* g, void* l) {
    __builtin_amdgcn_global_load_lds(
        (__attribute__((address_space(1))) void*)const_cast<void*>(g),
        (__attribute__((address_space(3))) void*)l, 16, 0, 0);
}

// ---------------------------------------------------------------------------
// Prep (merged): weight bf16 converts + RoPE tables [T][32] + RMSNorm.
// Grid 8448 x 256: [0,3072) w_qkv, [3072,4096) w_o, [4096,4352) tables,
// [4352,8448) rmsnorm (one block per row).
// ---------------------------------------------------------------------------
__global__ __launch_bounds__(256) void prep_k(const float* __restrict__ w_qkv,
                                              u16* __restrict__ wqkv_bf,
                                              const float* __restrict__ w_o,
                                              u16* __restrict__ wo_bf,
                                              float* __restrict__ cosT,
                                              float* __restrict__ sinT,
                                              const float* __restrict__ x,
                                              const float* __restrict__ rms_w,
                                              u16* __restrict__ xn) {
    __shared__ float ws_[4];
    int blk = blockIdx.x;
    int tid = threadIdx.x;
    if (blk < 3072) {
        int i = (blk * 256 + tid) * 4;
        float4 v = *(const float4*)&w_qkv[i];
        ushort4 o;
        o.x = f2bf(v.x); o.y = f2bf(v.y); o.z = f2bf(v.z); o.w = f2bf(v.w);
        *(ushort4*)&wqkv_bf[i] = o;
    } else if (blk < 4096) {
        int i = ((blk - 3072) * 256 + tid) * 4;
        float4 v = *(const float4*)&w_o[i];
        ushort4 o;
        o.x = f2bf(v.x); o.y = f2bf(v.y); o.z = f2bf(v.z); o.w = f2bf(v.w);
        *(ushort4*)&wo_bf[i] = o;
    } else if (blk < 4352) {
        int lin = (blk - 4096) * 256 + tid;   // 0..65535 = t*32+j
        int tt = lin >> 5, j = lin & 31;
        float inv = exp2f(-(float)j * (log2f(10000.0f) / 32.0f));
        float a = (float)tt * inv;
        cosT[lin] = cosf(a);
        sinT[lin] = sinf(a);
    } else {
        int row = blk - 4352;
        const float* xr = x + (size_t)row * Cc;
        float4 v = *(const float4*)&xr[tid * 4];
        float ss = v.x * v.x + v.y * v.y + v.z * v.z + v.w * v.w;
        #pragma unroll
        for (int off = 32; off > 0; off >>= 1) ss += __shfl_down(ss, off);
        if ((tid & 63) == 0) ws_[tid >> 6] = ss;
        __syncthreads();
        float tot = ws_[0] + ws_[1] + ws_[2] + ws_[3];
        float r = rsqrtf(tot * (1.0f / (float)Cc) + EPSV);
        float4 wv = *(const float4*)&rms_w[tid * 4];
        ushort4 o;
        o.x = f2bf(v.x * r * wv.x);
        o.y = f2bf(v.y * r * wv.y);
        o.z = f2bf(v.z * r * wv.z);
        o.w = f2bf(v.w * r * wv.w);
        *(ushort4*)&xn[(size_t)row * Cc + tid * 4] = o;
    }
}

// ---------------------------------------------------------------------------
// bf16 MFMA GEMM v2 (R19 winner): 128x64 tile, BK=64, 4 waves, 24KB LDS ->
// 6 blocks/CU. 2-barrier skeleton + source-chunk XOR swizzle (rule #21).
// ---------------------------------------------------------------------------
template<bool BF16OUT>
__global__ __launch_bounds__(256) void gemm_mfma_k(const u16* __restrict__ A,
                                                   const u16* __restrict__ W,
                                                   const float* __restrict__ bias,
                                                   void* __restrict__ Ov,
                                                   int M, int N, int K) {
    __shared__ __align__(16) u16 As[128 * 64];   // 16 KB
    __shared__ __align__(16) u16 Bs[64 * 64];    // 8 KB

    const int tid = threadIdx.x;
    const int w = tid >> 6;
    const int l = tid & 63;
    const int wr = w >> 1;
    const int wc = w & 1;
    const int q = l & 15;
    const int g = l >> 4;

    const int m0 = blockIdx.y * 128;
    const int n0 = blockIdx.x * 64;

    const int srow = l >> 3;
    const int cph = l & 7;
    const int cl = cph ^ srow;

    f32x4 acc[4][2];
    #pragma unroll
    for (int i = 0; i < 4; ++i)
        #pragma unroll
        for (int j = 0; j < 2; ++j)
            acc[i][j] = (f32x4){0.f, 0.f, 0.f, 0.f};

    const int nkt = K >> 6;
    for (int kt = 0; kt < nkt; ++kt) {
        const int k0 = kt << 6;
        __syncthreads();
        #pragma unroll
        for (int iss = 0; iss < 4; ++iss) {
            int r = w * 32 + iss * 8 + srow;
            gload_lds16(A + (size_t)(m0 + r) * K + k0 + cl * 8,
                        &As[(w * 32 + iss * 8) * 64]);
        }
        #pragma unroll
        for (int iss = 0; iss < 2; ++iss) {
            int r = w * 16 + iss * 8 + srow;
            gload_lds16(W + (size_t)(n0 + r) * K + k0 + cl * 8,
                        &Bs[(w * 16 + iss * 8) * 64]);
        }
        __syncthreads();

        #pragma unroll
        for (int kk = 0; kk < 2; ++kk) {
            Frag8 af[4], bf[2];
            const int ca = kk * 4 + g;
            #pragma unroll
            for (int i = 0; i < 4; ++i) {
                int ra = wr * 64 + i * 16 + q;
                af[i] = *(const Frag8*)&As[ra * 64 + ((ca ^ (ra & 7)) * 8)];
            }
            #pragma unroll
            for (int j = 0; j < 2; ++j) {
                int rb = wc * 32 + j * 16 + q;
                bf[j] = *(const Frag8*)&Bs[rb * 64 + ((ca ^ (rb & 7)) * 8)];
            }
            #pragma unroll
            for (int i = 0; i < 4; ++i)
                #pragma unroll
                for (int j = 0; j < 2; ++j)
                    acc[i][j] = __builtin_amdgcn_mfma_f32_16x16x32_bf16(
                        af[i].b, bf[j].b, acc[i][j], 0, 0, 0);
        }
    }

    #pragma unroll
    for (int i = 0; i < 4; ++i) {
        int row = m0 + wr * 64 + i * 16 + g * 4;
        #pragma unroll
        for (int j = 0; j < 2; ++j) {
            int col = n0 + wc * 32 + j * 16 + q;
            float bb = bias[col];
            #pragma unroll
            for (int r2 = 0; r2 < 4; ++r2) {
                float val = acc[i][j][r2] + bb;
                if (BF16OUT)
                    ((u16*)Ov)[(size_t)(row + r2) * N + col] = f2bf(val);
                else
                    ((float*)Ov)[(size_t)(row + r2) * N + col] = val;
            }
        }
    }
}

// ---------------------------------------------------------------------------
// RoPE + repack v2: qkv_bf16 [b,t,3,h,64] ->
//   Qb [bh][t][64] bf16 (Q pre-scaled by 0.125*log2e)  [unchanged layout]
//   KL [bh][tile][kk*4+g][lane][8] bf16  -- FRAGMENT-MAJOR
//   VL [bh][tile][kk*4+dg][lane][8] bf16 -- fragment-major, pi folded in
// Per-tile stride for KL/VL: 8 frags * 512 u16 = 4096 u16 (8 KB).
// ---------------------------------------------------------------------------
__global__ __launch_bounds__(256) void rope_pack_k(const u16* __restrict__ qkv,
                                                   const float* __restrict__ cosT,
                                                   const float* __restrict__ sinT,
                                                   u16* __restrict__ Qb,
                                                   u16* __restrict__ KL,
                                                   u16* __restrict__ VL) {
    const int jt = blockIdx.x;          // tile 0..31
    const int t0 = jt * 64;
    const int h = blockIdx.y, b = blockIdx.z;
    const int t = threadIdx.x;
    const int bh = b * Hh + h;
    __shared__ u16 Vs[64 * 64];
    constexpr float QSC = 0.125f * 1.44269504089f;   // 1/sqrt(D) * log2(e)
    const size_t tilebase = ((size_t)bh * 32 + jt) * 4096;

    // ---- stage V tile to LDS (row-major, bf16 passthrough) ----
    {
        int row = t >> 2, d16 = (t & 3) * 16;
        const u16* vp = qkv + (size_t)(b * Tt + t0 + row) * 3072 + 2048 + h * 64 + d16;
        *(uint4*)&Vs[row * 64 + d16]     = *(const uint4*)vp;
        *(uint4*)&Vs[row * 64 + d16 + 8] = *(const uint4*)(vp + 8);
    }

    // ---- RoPE on Q and K ----
    {
        int row = t >> 2, d0 = (t & 3) * 8;
        int g = row >> 4, q15 = row & 15, g2 = t & 3;
        size_t rb = (size_t)(b * Tt + t0 + row) * 3072 + h * 64;
        const u16* qp = qkv + rb;
        const u16* kp = qkv + rb + 1024;
        Frag8 qlo, qhi, klo, khi;
        qlo.v = *(const uint4*)&qp[d0];
        qhi.v = *(const uint4*)&qp[d0 + 32];
        klo.v = *(const uint4*)&kp[d0];
        khi.v = *(const uint4*)&kp[d0 + 32];
        const float* cp = &cosT[(t0 + row) * 32 + d0];
        const float* sp = &sinT[(t0 + row) * 32 + d0];
        float4 c0 = *(const float4*)cp, c1 = *(const float4*)(cp + 4);
        float4 s0 = *(const float4*)sp, s1 = *(const float4*)(sp + 4);
        float cc[8] = {c0.x, c0.y, c0.z, c0.w, c1.x, c1.y, c1.z, c1.w};
        float ss[8] = {s0.x, s0.y, s0.z, s0.w, s1.x, s1.y, s1.z, s1.w};
        Frag8 oql, oqh, okl, okh;
        #pragma unroll
        for (int i = 0; i < 8; ++i) {
            float ql = bf2f(qlo.u[i]), qh = bf2f(qhi.u[i]);
            float kl = bf2f(klo.u[i]), kh = bf2f(khi.u[i]);
            oql.u[i] = f2bf((ql * cc[i] - qh * ss[i]) * QSC);
            oqh.u[i] = f2bf((qh * cc[i] + ql * ss[i]) * QSC);
            okl.u[i] = f2bf(kl * cc[i] - kh * ss[i]);
            okh.u[i] = f2bf(kh * cc[i] + kl * ss[i]);
        }
        // Q: head-major rows (unchanged layout)
        u16* qd = Qb + ((size_t)bh * Tt + t0 + row) * 64;
        *(uint4*)&qd[d0]      = oql.v;
        *(uint4*)&qd[d0 + 32] = oqh.v;
        // K: fragment-major. okl -> (kk=0, chunk g2); okh -> (kk=1, chunk g2).
        *(uint4*)&KL[tilebase + (size_t)(0 * 4 + g) * 512 + (g2 * 16 + q15) * 8] = okl.v;
        *(uint4*)&KL[tilebase + (size_t)(1 * 4 + g) * 512 + (g2 * 16 + q15) * 8] = okh.v;
    }
    __syncthreads();

    // ---- V out: fragment-major with pi-permuted key slots ----
    {
        int d = t >> 2, kq = (t & 3) * 16;
        int dg = d >> 4, q15v = d & 15;
        int kkv = (t & 3) >> 1;            // slots >= 32 -> kk=1
        int g2a = ((t & 3) & 1) * 2;       // first chunk within this 16-slot run
        Frag8 a, b2;
        #pragma unroll
        for (int j = 0; j < 16; ++j) {
            int slot = kq + j;
            int key = ((slot >> 5) * 2 + ((slot >> 2) & 1)) * 16
                    + ((slot >> 3) & 3) * 4 + (slot & 3);
            u16 vv = Vs[key * 64 + d];
            if (j < 8) a.u[j] = vv; else b2.u[j - 8] = vv;
        }
        u16* base = VL + tilebase + (size_t)(kkv * 4 + dg) * 512;
        *(uint4*)&base[(g2a * 16 + q15v) * 8]       = a.v;
        *(uint4*)&base[((g2a + 1) * 16 + q15v) * 8] = b2.v;
    }
}

// ---------------------------------------------------------------------------
// MFMA flash attention v14: zero-LDS streaming + FULL REGISTER BUDGET.
// R24 failure diagnosis: compiler capped VGPR at 64 (targeting 8 waves/SIMD
// our 4096-wave grid never supplies) -> the 16 frag loads serialized through
// narrow register windows, exposing L2 latency. Fix: __launch_bounds__(256,4)
// (min 4 waves/EU -> 128 VGPR budget) so kf/vf/sacc/acco all live at once,
// and V loads issued BEFORE the exp2/pack phase so they hide under VALU.
// ---------------------------------------------------------------------------
__global__ __launch_bounds__(256, 4) void attn_mfma_k(const u16* __restrict__ Qb,
                                                      const u16* __restrict__ KL,
                                                      const u16* __restrict__ VL,
                                                      u16* __restrict__ out) {
    const int i = blockIdx.x;           // 0..1023
    int c, bh;
    if (i < 512) { c = 31 - (i >> 5); bh = i & 31; }        // heavy first
    else         { int k = i - 512; c = k >> 5; bh = k & 31; }
    const int b = bh >> 4, h = bh & 15;

    const int t = threadIdx.x;
    const int w4 = t >> 6;       // wave 0..3
    const int l = t & 63;
    const int q15 = l & 15;
    const int g2 = l >> 4;

    // ---- Q fragments (exp2-domain scale pre-folded) ----
    Frag8 qf[2];
    {
        int qrow = c * 64 + w4 * 16 + q15;
        const u16* qp = Qb + ((size_t)bh * Tt + qrow) * 64;
        qf[0] = *(const Frag8*)&qp[g2 * 8];
        qf[1] = *(const Frag8*)&qp[32 + g2 * 8];
    }

    Frag8 ones;
    #pragma unroll
    for (int e = 0; e < 8; ++e) ones.u[e] = 0x3F80;   // bf16 1.0

    f32x4 acco[4];
    #pragma unroll
    for (int dg = 0; dg < 4; ++dg) acco[dg] = (f32x4){0.f, 0.f, 0.f, 0.f};
    f32x4 acc_l = (f32x4){0.f, 0.f, 0.f, 0.f};

    // fragment-major bases; lane offset l*8 u16 = 16B, contiguous per wave.
    const u16* kp0 = KL + ((size_t)bh * 32) * 4096 + l * 8;
    const u16* kp1 = kp0 + 2048;     // frags 4..7
    const u16* vp0 = VL + ((size_t)bh * 32) * 4096 + l * 8;
    const u16* vp1 = vp0 + 2048;

    for (int j = 0; j <= c; ++j) {
        // ---- K fragment loads (batched; full budget lets them all hoist) ----
        Frag8 kf[2][4];
        #pragma unroll
        for (int g = 0; g < 4; ++g) {
            kf[0][g] = *(const Frag8*)&kp0[g * 512];
            kf[1][g] = *(const Frag8*)&kp1[g * 512];
        }
        // ---- QK^T (swapped): S^T[key][q], log2 domain ----
        f32x4 sacc[4];
        __builtin_amdgcn_s_setprio(1);
        #pragma unroll
        for (int g = 0; g < 4; ++g) {
            sacc[g] = (f32x4){0.f, 0.f, 0.f, 0.f};
            sacc[g] = __builtin_amdgcn_mfma_f32_16x16x32_bf16(
                kf[0][g].b, qf[0].b, sacc[g], 0, 0, 0);
            sacc[g] = __builtin_amdgcn_mfma_f32_16x16x32_bf16(
                kf[1][g].b, qf[1].b, sacc[g], 0, 0, 0);
        }
        __builtin_amdgcn_s_setprio(0);

        // ---- V fragment loads issued NOW: latency hides under mask+exp2 ----
        Frag8 vf[2][4];
        #pragma unroll
        for (int dg = 0; dg < 4; ++dg) {
            vf[0][dg] = *(const Frag8*)&vp0[dg * 512];
            vf[1][dg] = *(const Frag8*)&vp1[dg * 512];
        }

        if (j == c) {   // diagonal tile: causal mask (true key order)
            #pragma unroll
            for (int g = 0; g < 4; ++g)
                #pragma unroll
                for (int r = 0; r < 4; ++r)
                    if (g * 16 + g2 * 4 + r > w4 * 16 + q15) sacc[g][r] = -1e30f;
        }

        // ---- P = exp2(S) straight into PV A-fragments (pi-VL) ----
        Frag8 pa[2];
        #pragma unroll
        for (int kk = 0; kk < 2; ++kk)
            #pragma unroll
            for (int e = 0; e < 8; ++e)
                pa[kk].b[e] = (__bf16)exp2f(sacc[2 * kk + (e >> 2)][e & 3]);

        // ---- l-sum + PV ----
        __builtin_amdgcn_s_setprio(1);
        acc_l = __builtin_amdgcn_mfma_f32_16x16x32_bf16(pa[0].b, ones.b, acc_l, 0, 0, 0);
        acc_l = __builtin_amdgcn_mfma_f32_16x16x32_bf16(pa[1].b, ones.b, acc_l, 0, 0, 0);
        #pragma unroll
        for (int dg = 0; dg < 4; ++dg) {
            acco[dg] = __builtin_amdgcn_mfma_f32_16x16x32_bf16(
                pa[0].b, vf[0][dg].b, acco[dg], 0, 0, 0);
            acco[dg] = __builtin_amdgcn_mfma_f32_16x16x32_bf16(
                pa[1].b, vf[1][dg].b, acco[dg], 0, 0, 0);
        }
        __builtin_amdgcn_s_setprio(0);

        kp0 += 4096; kp1 += 4096;
        vp0 += 4096; vp1 += 4096;
    }

    // ---- epilogue: acc_l[r] is the row sum for row g2*4+r ----
    float lr[4];
    #pragma unroll
    for (int r = 0; r < 4; ++r) lr[r] = 1.f / acc_l[r];
    const int qbase = c * 64 + w4 * 16;
    #pragma unroll
    for (int dg = 0; dg < 4; ++dg)
        #pragma unroll
        for (int r = 0; r < 4; ++r)
            out[((size_t)(b * Tt + qbase + g2 * 4 + r)) * Cc + h * 64 + dg * 16 + q15] =
                f2bf(acco[dg][r] * lr[r]);
}

// ---------------------------------------------------------------------------
// Launch
// ---------------------------------------------------------------------------
extern "C" void kernel_launch(void* const* d_in, const int* in_sizes, int n_in,
                              void* d_out, int out_size, void* d_ws, size_t ws_size,
                              hipStream_t stream) {
    const float* x      = (const float*)d_in[0];
    const float* w_qkv  = (const float*)d_in[2];
    const float* b_qkv  = (const float*)d_in[3];
    const float* w_o    = (const float*)d_in[4];
    const float* b_o    = (const float*)d_in[5];
    const float* rms_w  = (const float*)d_in[6];
    float* out = (float*)d_out;

    char* ws = (char*)d_ws;
    u16*   xn_bf   = (u16*)ws;                                   // 8 MB [0,8)
    u16*   KL      = (u16*)(ws + (size_t)(8 << 20));             // 8 MB [8,16)
    u16*   VL      = (u16*)(ws + (size_t)(16 << 20));            // 8 MB [16,24)
    u16*   Qb      = (u16*)(ws + (size_t)(24 << 20));            // 8 MB [24,32)
    u16*   qkvb    = (u16*)(ws + (size_t)(32 << 20));            // 24 MB [32,56)
    u16*   wqkv_bf = (u16*)(ws + (size_t)(56 << 20));            // 6 MB [56,62)
    u16*   wo_bf   = (u16*)(ws + (size_t)(62 << 20));            // 2 MB [62,64)
    float* cosT    = (float*)(ws + (size_t)(64 << 20));          // 256 KB
    float* sinT    = (float*)(ws + (size_t)(64 << 20) + (1 << 18));
    u16*   attn_bf = xn_bf;   // xn dead after QKV GEMM

    prep_k<<<dim3(8448), dim3(256), 0, stream>>>(w_qkv, wqkv_bf, w_o, wo_bf,
                                                 cosT, sinT, x, rms_w, xn_bf);
    gemm_mfma_k<true><<<dim3(3 * Cc / 64, M_ROWS / 128), dim3(256), 0, stream>>>(
        xn_bf, wqkv_bf, b_qkv, qkvb, M_ROWS, 3 * Cc, Cc);
    rope_pack_k<<<dim3(Tt / 64, Hh, Bb), dim3(256), 0, stream>>>(
        qkvb, cosT, sinT, Qb, KL, VL);
    attn_mfma_k<<<dim3(1024), dim3(256), 0, stream>>>(Qb, KL, VL, attn_bf);
    gemm_mfma_k<false><<<dim3(Cc / 64, M_ROWS / 128), dim3(256), 0, stream>>>(
        attn_bf, wo_bf, b_o, out, M_ROWS, Cc, Cc);
}